// Round 26
// baseline (40.027 us; speedup 1.0000x reference)
//
#include <hip/hip_runtime.h>

typedef unsigned long long u64;

#define BB 16
#define CC 3
#define AA 9
#define MM 32
#define KK 8
#define HWSZ 16384
#define NN (AA*HWSZ)

#define KEYS16_WORDS ((size_t)BB*NN/2)          // ushort keys, u32 words
#define NBLK (BB*64)                            // 1024 k_main blocks
#define HBLK 16
#define SUMMASK ((1ull<<44) - 1ull)
#define ONECNT  (1ull<<44)

// stats2 row: [0]=np [1]=k [2]=obj(sum objp) [3]=cls [4]=loc [5]=topk
#define S2_NP 0
#define S2_K  1
#define S2_OBJ 2
#define S2_CLS 3
#define S2_LOC 4
#define S2_TOPK 5

__device__ __forceinline__ unsigned calc_k(unsigned np, unsigned nn) {
  if (np == 0u) return (nn > 0u) ? ((nn/10u > 1u) ? nn/10u : 1u) : 0u;
  return (3u*np < nn) ? 3u*np : nn;
}

// 256-thread parallel "r-th from top" select; per-thread inputs (cnt,sum) for its bin.
__device__ __forceinline__ void sel1(unsigned lc, float ls, unsigned r,
                                     unsigned* s_c, float* s_s,
                                     unsigned* s_u, float* s_f,
                                     unsigned& bin_out, unsigned& r_out, float& sab_out)
{
  const int t = threadIdx.x;
  s_c[t] = lc; s_s[t] = ls;
  __syncthreads();
  for (int off = 1; off < 256; off <<= 1) {            // suffix inclusive scan
    unsigned ac = s_c[t]; float as = s_s[t];
    unsigned bc = 0; float bs = 0.f;
    if (t + off < 256) { bc = s_c[t + off]; bs = s_s[t + off]; }
    __syncthreads();
    s_c[t] = ac + bc; s_s[t] = as + bs;
    __syncthreads();
  }
  bool win = (t == 255) ? (s_c[255] >= r) : (s_c[t] >= r && s_c[t+1] < r);
  if (win) {                                           // exactly one thread
    unsigned cum = (t < 255) ? s_c[t+1] : 0u;
    float sab = (t < 255) ? s_s[t+1] : 0.f;
    s_u[0] = (unsigned)t; s_u[1] = r - cum; s_f[0] = sab;
  }
  __syncthreads();
  bin_out = s_u[0]; r_out = s_u[1]; sab_out = s_f[0];
  __syncthreads();
}

// ---------------- K1: per-anchor losses, 16-bit keys; per-block hist/stat slices ---------
__global__ __launch_bounds__(256, 4) void k_main(
    const float* __restrict__ pred,
    const float* __restrict__ gtb, const int* __restrict__ gtl,
    unsigned short* __restrict__ keys16, unsigned* __restrict__ stats_pb,
    u64* __restrict__ hist_pb)
{
  __shared__ float4 s_box[MM];
  __shared__ float s_area[MM], s_gx[MM], s_gy[MM], s_gw[MM], s_gh[MM];
  __shared__ int s_lab[MM];
  __shared__ int s_list[MM];
  __shared__ int s_cnt;
  __shared__ u64 s_h64[8][257];        // packed cnt|sum replicas, +1 pad
  __shared__ unsigned s_ri[2];
  __shared__ float s_rf[3];
  __shared__ unsigned s_plist[AA*256]; // pos items: hw | a<<14 | jb<<18
  __shared__ unsigned s_pcnt;

  const int tid = threadIdx.x;
  const int b = blockIdx.x >> 6;
  const int t6 = blockIdx.x & 63;
  const int tr = t6 >> 3, tc = t6 & 7;            // 8x8 tiles of 16x16 px
  const int hrow = tr*16 + (tid >> 4);
  const int wcol = tc*16 + (tid & 15);
  const int hw = hrow*128 + wcol;

  for (int i = tid; i < 8*257; i += 256) (&s_h64[0][0])[i] = 0ull;
  if (tid == 0) { s_ri[0] = 0u; s_ri[1] = 0u; s_pcnt = 0u; }
  if (tid < 3) s_rf[tid] = 0.f;
  if (tid < MM) {
    float x1 = gtb[((size_t)b*MM + tid)*4 + 0];
    float y1 = gtb[((size_t)b*MM + tid)*4 + 1];
    float x2 = gtb[((size_t)b*MM + tid)*4 + 2];
    float y2 = gtb[((size_t)b*MM + tid)*4 + 3];
    s_box[tid] = make_float4(x1, y1, x2, y2);
    s_area[tid] = (x2 - x1) * (y2 - y1);
    s_gx[tid] = (x1 + x2) * 0.5f;
    s_gy[tid] = (y1 + y2) * 0.5f;
    s_gw[tid] = fmaxf(x2 - x1, 1e-6f);
    s_gh[tid] = fmaxf(y2 - y1, 1e-6f);
    s_lab[tid] = gtl[(size_t)b*MM + tid];
  }
  __syncthreads();

  // cull boxes that cannot overlap any anchor of this tile (margin 46 > 45.25)
  if (tid < 64) {
    const float cxlo = (float)(tc*64 + 2), cxhi = cxlo + 60.f;
    const float cylo = (float)(tr*64 + 2), cyhi = cylo + 60.f;
    bool keep = false;
    if (tid < MM) {
      float4 bx = s_box[tid];
      keep = (bx.z >= cxlo - 46.f) && (bx.x <= cxhi + 46.f) &&
             (bx.w >= cylo - 46.f) && (bx.y <= cyhi + 46.f);
    }
    unsigned long long mask = __ballot(keep);
    if (keep) s_list[__popcll(mask & ((1ull << tid) - 1ull))] = tid;
    if (tid == 0) s_cnt = (int)__popcll(mask);
  }
  __syncthreads();

  // issue the 9 obj-channel loads EARLY: their ~900cy HBM latency overlaps the IoU loop
  const float* pb = pred + (size_t)b * (AA*KK) * HWSZ + hw;
  float xo[AA];
#pragma unroll
  for (int a = 0; a < AA; ++a) xo[a] = pb[(size_t)((a*KK + 4) * HWSZ)];

  // anchor coords, bit-exact reproduction of make_anchors (scales are powers of 2)
  const float cx = ((float)wcol + 0.5f) * 4.0f;
  const float cy = ((float)hrow + 0.5f) * 4.0f;
  float AX1[AA], AY1[AA], AX2[AA], AY2[AA], AREA[AA];
  {
    const float S0[3] = {16.f, 32.f, 64.f};
    const float Q0[3] = {0.70710678118654752440f, 1.0f, 1.41421356237309504880f};
#pragma unroll
    for (int i = 0; i < 3; ++i)
#pragma unroll
      for (int jj = 0; jj < 3; ++jj) {
        int a = i*3 + jj;
        float w2 = S0[i] * Q0[jj] * 0.5f;
        float h2 = (S0[i] / Q0[jj]) * 0.5f;
        float x1 = cx - w2, x2 = cx + w2;
        float y1 = cy - h2, y2 = cy + h2;
        AX1[a]=x1; AX2[a]=x2; AY1[a]=y1; AY2[a]=y2;
        AREA[a] = (x2 - x1) * (y2 - y1);
      }
  }

  float bnum[AA], bden[AA]; int bi[AA];
#pragma unroll
  for (int a = 0; a < AA; ++a) { bnum[a] = 0.f; bden[a] = 1.f; bi[a] = 0; }

  const int cnt = s_cnt;
  for (int jj = 0; jj < cnt; ++jj) {
    const int j = s_list[jj];
    const float4 bx = s_box[j];
    const float ba = s_area[j];
#pragma unroll
    for (int a = 0; a < AA; ++a) {
      float lx = fmaxf(AX1[a], bx.x);
      float ly = fmaxf(AY1[a], bx.y);
      float rx = fminf(AX2[a], bx.z);
      float ry = fminf(AY2[a], bx.w);
      float wx = fmaxf(rx - lx, 0.f);
      float wy = fmaxf(ry - ly, 0.f);
      float inter = wx * wy;
      float den = (AREA[a] + ba) - inter;        // union >= 256 >> 1e-9
      bool bt = inter * bden[a] > bnum[a] * den; // iou_j > iou_best (ascending j)
      bnum[a] = bt ? inter : bnum[a];
      bden[a] = bt ? den : bden[a];
      bi[a]   = bt ? j : bi[a];
    }
  }

  // tile-major key layout: [b][a][t6][tid] -> waves store 512B contiguous
  unsigned short* kout = keys16 + ((size_t)b * AA) * HWSZ + (t6 << 8) + tid;

  const int rep = tid & 7;
  unsigned npos = 0, nneg = 0;
  float objp = 0.f;

#pragma unroll
  for (int a = 0; a < AA; ++a) {
    // multiply-compare: bden > 0 always; 0.5*bden exact
    bool pos = bnum[a] >= 0.5f * bden[a];
    bool neg = bnum[a] < 0.3f * bden[a];

    float x = xo[a];
    float e = __expf(-fabsf(x));
    float ol = fmaxf(x, 0.f) - (pos ? x : 0.f) + __logf(1.f + e);

    unsigned key = 0u;
    if (neg) {
      key = __float_as_uint(ol);
      ++nneg;
      atomicAdd(&s_h64[rep][key >> 24], ONECNT | (u64)(ol * 1048576.0f + 0.5f));
    }
    kout[(size_t)a * HWSZ] = (unsigned short)(key >> 16);

    if (pos) {
      ++npos;
      objp += ol;
      unsigned idx = atomicAdd(&s_pcnt, 1u);
      s_plist[idx] = (unsigned)hw | ((unsigned)a << 14) | ((unsigned)bi[a] << 18);
    }
  }

  __syncthreads();   // s_plist / s_pcnt complete

  // ---- phase 2: process pos anchors in parallel (no divergent heavy branch) ----
  float cls2 = 0.f, loc2 = 0.f;
  {
    const int pcnt = (int)s_pcnt;
    const float* pball = pred + (size_t)b * (AA*KK) * HWSZ;
    for (int i = tid; i < pcnt; i += 256) {
      unsigned it = s_plist[i];
      int hw2 = (int)(it & 16383u);
      int a2  = (int)((it >> 14) & 15u);
      int jb  = (int)(it >> 18);
      int w2c = hw2 & 127, h2r = hw2 >> 7;
      float cx2 = ((float)w2c + 0.5f) * 4.0f;
      float cy2 = ((float)h2r + 0.5f) * 4.0f;
      int si = a2 / 3, rj = a2 - si*3;
      float s0 = (si == 0) ? 16.f : ((si == 1) ? 32.f : 64.f);
      float q0 = (rj == 0) ? 0.70710678118654752440f : ((rj == 1) ? 1.0f : 1.41421356237309504880f);
      float w2 = s0 * q0 * 0.5f;
      float h2 = (s0 / q0) * 0.5f;
      float ax1 = cx2 - w2, ax2 = cx2 + w2;
      float ay1 = cy2 - h2, ay2 = cy2 + h2;

      const float* pp = pball + hw2;
      float c0 = pp[(size_t)((a2*KK + 5) * HWSZ)];
      float c1 = pp[(size_t)((a2*KK + 6) * HWSZ)];
      float c2 = pp[(size_t)((a2*KK + 7) * HWSZ)];
      int lab = s_lab[jb];
      int tgt = lab - 1; tgt = tgt < 0 ? 0 : (tgt > CC-1 ? CC-1 : tgt);
      float m = fmaxf(fmaxf(c0, c1), c2);
      float lse = m + __logf(__expf(c0-m) + __expf(c1-m) + __expf(c2-m));
      float ct = (tgt == 0) ? c0 : ((tgt == 1) ? c1 : c2);
      cls2 += lse - ct;

      float axc = (ax1 + ax2) * 0.5f;
      float ayc = (ay1 + ay2) * 0.5f;
      float aw = fmaxf(ax2 - ax1, 1e-6f);
      float ah = fmaxf(ay2 - ay1, 1e-6f);
      float t0 = (s_gx[jb] - axc) / aw;
      float t1 = (s_gy[jb] - ayc) / ah;
      float t2 = __logf(s_gw[jb] / aw);
      float t3 = __logf(s_gh[jb] / ah);
      float p0 = pp[(size_t)((a2*KK + 0) * HWSZ)];
      float p1 = pp[(size_t)((a2*KK + 1) * HWSZ)];
      float p2 = pp[(size_t)((a2*KK + 2) * HWSZ)];
      float p3 = pp[(size_t)((a2*KK + 3) * HWSZ)];
      float l = 0.f, d, ad;
      d = p0-t0; ad = fabsf(d); l += (ad < 1.f) ? 0.5f*d*d : ad - 0.5f;
      d = p1-t1; ad = fabsf(d); l += (ad < 1.f) ? 0.5f*d*d : ad - 0.5f;
      d = p2-t2; ad = fabsf(d); l += (ad < 1.f) ? 0.5f*d*d : ad - 0.5f;
      d = p3-t3; ad = fabsf(d); l += (ad < 1.f) ? 0.5f*d*d : ad - 0.5f;
      loc2 += l;
    }
  }

  // wave-level reduction, one atomic per wave per counter
#pragma unroll
  for (int off = 32; off; off >>= 1) {
    npos += __shfl_down(npos, off);
    nneg += __shfl_down(nneg, off);
    objp += __shfl_down(objp, off);
    cls2 += __shfl_down(cls2, off);
    loc2 += __shfl_down(loc2, off);
  }
  if ((tid & 63) == 0) {
    atomicAdd(&s_ri[0], npos);
    atomicAdd(&s_ri[1], nneg);
    atomicAdd(&s_rf[0], objp);
    atomicAdd(&s_rf[1], cls2);
    atomicAdd(&s_rf[2], loc2);
  }
  __syncthreads();

  // owner-writes: this block's stat row + hist slice (plain stores, no zeroing needed)
  unsigned* srow = stats_pb + (size_t)blockIdx.x * 8;
  if (tid == 0) { srow[0] = s_ri[0]; srow[1] = s_ri[1]; }
  else if (tid == 1) ((float*)srow)[2] = s_rf[0];
  else if (tid == 2) ((float*)srow)[3] = s_rf[1];
  else if (tid == 3) ((float*)srow)[4] = s_rf[2];

  u64 m = 0ull;
#pragma unroll
  for (int r = 0; r < 8; ++r) m += s_h64[r][tid];
  hist_pb[(size_t)blockIdx.x * 256 + tid] = m;
}

// ---- H1: reduce per-block hists, scan 16-bit keys, write own h1 slice ----
__global__ __launch_bounds__(256) void k_h1(
    const unsigned short* __restrict__ keys16, const unsigned* __restrict__ stats_pb,
    const u64* __restrict__ hist_pb, unsigned* __restrict__ h1_pb,
    unsigned* __restrict__ cnt)
{
  __shared__ unsigned s_c[256]; __shared__ float s_s[256];
  __shared__ unsigned s_u[2];   __shared__ float s_f[1];
  __shared__ unsigned s_hc[8][257];
  __shared__ unsigned s_np, s_nn;
  const int tid = threadIdx.x;
  const int b = blockIdx.x >> 4;                  // 16 blocks/image

  if (tid == 0) cnt[0] = 0u;                      // reset combine counter (dup stores benign)

  if (tid < 64) {
    unsigned np = stats_pb[(size_t)(b*64 + tid)*8 + 0];
    unsigned nn = stats_pb[(size_t)(b*64 + tid)*8 + 1];
#pragma unroll
    for (int off = 32; off; off >>= 1) { np += __shfl_down(np, off); nn += __shfl_down(nn, off); }
    if (tid == 0) { s_np = np; s_nn = nn; }
  }
  __syncthreads();
  const unsigned k = calc_k(s_np, s_nn);
  unsigned* hout = h1_pb + (size_t)(blockIdx.x) * 256;   // own slice (16 per image)
  if (k == 0u) { hout[tid] = 0u; return; }

  // reduce 64 per-block hist slices for this image (order-fixed, integer-exact)
  u64 hv = 0ull;
  {
    const u64* hp = hist_pb + (size_t)b * 64 * 256 + tid;
#pragma unroll 8
    for (int i = 0; i < 64; ++i) hv += hp[(size_t)i * 256];
  }
  unsigned bin0, r0; float sab;
  sel1((unsigned)(hv >> 44), (float)(hv & SUMMASK) * 0x1p-20f, k,
       s_c, s_s, s_u, s_f, bin0, r0, sab);

  for (int i = tid; i < 8*257; i += 256) (&s_hc[0][0])[i] = 0u;
  __syncthreads();

  const int rep = tid & 7;
  // 9216 keys/block = 2304 uint2 (4 ushorts each) / 256 threads = 9 iters
  const uint2* kp = (const uint2*)(keys16 + (size_t)b * NN) +
                    (size_t)(blockIdx.x & 15) * 2304;
#pragma unroll
  for (int j = 0; j < 9; ++j) {
    uint2 v = kp[j*256 + tid];
    unsigned k0 = v.x & 0xFFFFu, k1 = v.x >> 16;
    unsigned k2 = v.y & 0xFFFFu, k3 = v.y >> 16;
    if ((k0 >> 8) == bin0) atomicAdd(&s_hc[rep][k0 & 255u], 1u);
    if ((k1 >> 8) == bin0) atomicAdd(&s_hc[rep][k1 & 255u], 1u);
    if ((k2 >> 8) == bin0) atomicAdd(&s_hc[rep][k2 & 255u], 1u);
    if ((k3 >> 8) == bin0) atomicAdd(&s_hc[rep][k3 & 255u], 1u);
  }
  __syncthreads();

  unsigned c = 0;
#pragma unroll
  for (int r = 0; r < 8; ++r) c += s_hc[r][tid];
  hout[tid] = c;                                  // plain store, full overwrite
}

// ---- FIN: per-image reduce + two-level select (16 blocks); last-done block combines ----
// Bins above bin1 summed from packed hist (2^-20 fixed point, error ~5e-7 on loss);
// bin0's interior at mid-bin (16-bit bins, unbiased): worst-case loss error ~4e-3.
__global__ __launch_bounds__(256) void k_fin(
    const unsigned* __restrict__ stats_pb, const u64* __restrict__ hist_pb,
    const unsigned* __restrict__ h1_pb, unsigned* __restrict__ stats2,
    unsigned* __restrict__ counter, float* __restrict__ out)
{
  __shared__ unsigned s_c[256]; __shared__ float s_s[256];
  __shared__ unsigned s_u[2];   __shared__ float s_f[1];
  __shared__ unsigned s_np, s_nn;
  __shared__ float s_obj, s_cls, s_loc;
  __shared__ unsigned s_prev;
  const int b = blockIdx.x;
  const int tid = threadIdx.x;

  if (tid < 64) {
    const unsigned* sp = stats_pb + (size_t)(b*64 + tid)*8;
    unsigned np = sp[0], nn = sp[1];
    float ob = ((const float*)sp)[2];
    float cl = ((const float*)sp)[3];
    float lo = ((const float*)sp)[4];
#pragma unroll
    for (int off = 32; off; off >>= 1) {
      np += __shfl_down(np, off); nn += __shfl_down(nn, off);
      ob += __shfl_down(ob, off); cl += __shfl_down(cl, off); lo += __shfl_down(lo, off);
    }
    if (tid == 0) { s_np = np; s_nn = nn; s_obj = ob; s_cls = cl; s_loc = lo; }
  }
  __syncthreads();
  const unsigned k = calc_k(s_np, s_nn);
  float topk = 0.f;
  if (k) {
    u64 hv = 0ull;
    {
      const u64* hp = hist_pb + (size_t)b * 64 * 256 + tid;
#pragma unroll 8
      for (int i = 0; i < 64; ++i) hv += hp[(size_t)i * 256];
    }
    unsigned bin0, r0, bin1, r1;
    float sab0, sab1;
    sel1((unsigned)(hv >> 44), (float)(hv & SUMMASK) * 0x1p-20f, k,
         s_c, s_s, s_u, s_f, bin0, r0, sab0);
    unsigned c1 = 0;
    {
      const unsigned* hp1 = h1_pb + (size_t)b * 16 * 256 + tid;
#pragma unroll
      for (int i = 0; i < 16; ++i) c1 += hp1[i * 256];
    }
    float mid = __uint_as_float((bin0 << 24) | ((unsigned)tid << 16) | 0x8000u);
    sel1(c1, (float)c1 * mid, r0, s_c, s_s, s_u, s_f, bin1, r1, sab1);
    float mid1 = __uint_as_float((bin0 << 24) | (bin1 << 16) | 0x8000u);
    topk = sab0 + sab1 + (float)r1 * mid1;
  }
  if (tid == 0) {
    unsigned* s2 = stats2 + b * 8;
    __hip_atomic_store(&s2[S2_NP], s_np, __ATOMIC_RELAXED, __HIP_MEMORY_SCOPE_AGENT);
    __hip_atomic_store(&s2[S2_K],  k,    __ATOMIC_RELAXED, __HIP_MEMORY_SCOPE_AGENT);
    __hip_atomic_store((float*)&s2[S2_OBJ], s_obj, __ATOMIC_RELAXED, __HIP_MEMORY_SCOPE_AGENT);
    __hip_atomic_store((float*)&s2[S2_CLS], s_cls, __ATOMIC_RELAXED, __HIP_MEMORY_SCOPE_AGENT);
    __hip_atomic_store((float*)&s2[S2_LOC], s_loc, __ATOMIC_RELAXED, __HIP_MEMORY_SCOPE_AGENT);
    __hip_atomic_store((float*)&s2[S2_TOPK], topk, __ATOMIC_RELAXED, __HIP_MEMORY_SCOPE_AGENT);
    __threadfence();   // release prior stores device-wide
    s_prev = __hip_atomic_fetch_add(counter, 1u, __ATOMIC_ACQ_REL, __HIP_MEMORY_SCOPE_AGENT);
  }
  __syncthreads();

  if (s_prev == (unsigned)(BB - 1) && tid < 64) {
    __threadfence();
    unsigned np = 0, kk = 0;
    float obj = 0.f, cls = 0.f, loc = 0.f;
    if (tid < BB) {
      unsigned* s2 = stats2 + tid * 8;
      np  = __hip_atomic_load(&s2[S2_NP], __ATOMIC_RELAXED, __HIP_MEMORY_SCOPE_AGENT);
      kk  = __hip_atomic_load(&s2[S2_K],  __ATOMIC_RELAXED, __HIP_MEMORY_SCOPE_AGENT);
      obj = __hip_atomic_load((float*)&s2[S2_OBJ], __ATOMIC_RELAXED, __HIP_MEMORY_SCOPE_AGENT)
          + __hip_atomic_load((float*)&s2[S2_TOPK], __ATOMIC_ACQUIRE, __HIP_MEMORY_SCOPE_AGENT);
      cls = __hip_atomic_load((float*)&s2[S2_CLS], __ATOMIC_RELAXED, __HIP_MEMORY_SCOPE_AGENT);
      loc = __hip_atomic_load((float*)&s2[S2_LOC], __ATOMIC_RELAXED, __HIP_MEMORY_SCOPE_AGENT);
    }
#pragma unroll
    for (int off = 8; off; off >>= 1) {
      np  += __shfl_down(np, off);
      kk  += __shfl_down(kk, off);
      obj += __shfl_down(obj, off);
      cls += __shfl_down(cls, off);
      loc += __shfl_down(loc, off);
    }
    if (tid == 0) {
      unsigned ts = np + kk;
      float dp  = (float)(np > 1u ? np : 1u);
      float dob = (float)(ts > 1u ? ts : 1u);
      float lo = obj / dob, lc = cls / dp, ll = loc / dp;
      out[0] = lo;
      out[1] = lc;
      out[2] = ll;
      out[3] = 2.f*ll + lc + lo;
    }
  }
}

extern "C" void kernel_launch(void* const* d_in, const int* in_sizes, int n_in,
                              void* d_out, int out_size, void* d_ws, size_t ws_size,
                              hipStream_t stream)
{
  const float* pred = (const float*)d_in[0];
  // d_in[1] (anchors) reproduced bit-exactly on device; unused
  const float* gtb  = (const float*)d_in[2];
  const int*   gtl  = (const int*)d_in[3];
  float* out = (float*)d_out;

  unsigned* ws    = (unsigned*)d_ws;
  unsigned short* keys16 = (unsigned short*)ws;          // BB*NN ushorts
  u64* hist_pb    = (u64*)(ws + KEYS16_WORDS);           // 1024*256 u64 (8B-aligned)
  unsigned* stats_pb = (unsigned*)(hist_pb + (size_t)NBLK*256);  // 1024*8 u32
  unsigned* h1_pb = stats_pb + NBLK*8;                   // 256*256 u32
  unsigned* stats2 = h1_pb + 256*256;                    // 16*8 u32
  unsigned* cnt   = stats2 + BB*8;                       // 4 u32

  k_main<<<NBLK, 256, 0, stream>>>(pred, gtb, gtl, keys16, stats_pb, hist_pb);
  k_h1<<<BB*HBLK, 256, 0, stream>>>(keys16, stats_pb, hist_pb, h1_pb, cnt);
  k_fin<<<BB, 256, 0, stream>>>(stats_pb, hist_pb, h1_pb, stats2, cnt, out);
}

// Round 27
// 37.731 us; speedup vs baseline: 1.0609x; 1.0609x over previous
//
#include <hip/hip_runtime.h>

typedef unsigned long long u64;

#define BB 16
#define CC 3
#define AA 9
#define MM 32
#define KK 8
#define HWSZ 16384
#define NN (AA*HWSZ)

#define STATS_STRIDE 32
#define ST_NPOS 0
#define ST_NNEG 1
#define ST_OBJP 2
#define ST_CLS  3
#define ST_LOC  4
#define ST_K    5
#define ST_TOPK 6

#define KEYS16_WORDS ((size_t)BB*NN/2)          // ushort keys, u32 words
#define STATS_WORDS (BB*STATS_STRIDE)           // 512
#define HIST0_WORDS (BB*512)                    // u32 words backing BB*256 u64 bins
#define H1_WORDS    (BB*256)                    // 4096 (256 counts / image)
#define CNT_WORDS   4
#define ZERO_WORDS  (STATS_WORDS + HIST0_WORDS + H1_WORDS + CNT_WORDS)  // 12804

#define HBLK 16
#define SUMMASK ((1ull<<44) - 1ull)
#define ONECNT  (1ull<<44)

__device__ __forceinline__ unsigned calc_k(unsigned np, unsigned nn) {
  if (np == 0u) return (nn > 0u) ? ((nn/10u > 1u) ? nn/10u : 1u) : 0u;
  return (3u*np < nn) ? 3u*np : nn;
}

// 256-thread parallel "r-th from top" select; per-thread inputs (cnt,sum) for its bin.
__device__ __forceinline__ void sel1(unsigned lc, float ls, unsigned r,
                                     unsigned* s_c, float* s_s,
                                     unsigned* s_u, float* s_f,
                                     unsigned& bin_out, unsigned& r_out, float& sab_out)
{
  const int t = threadIdx.x;
  s_c[t] = lc; s_s[t] = ls;
  __syncthreads();
  for (int off = 1; off < 256; off <<= 1) {            // suffix inclusive scan
    unsigned ac = s_c[t]; float as = s_s[t];
    unsigned bc = 0; float bs = 0.f;
    if (t + off < 256) { bc = s_c[t + off]; bs = s_s[t + off]; }
    __syncthreads();
    s_c[t] = ac + bc; s_s[t] = as + bs;
    __syncthreads();
  }
  bool win = (t == 255) ? (s_c[255] >= r) : (s_c[t] >= r && s_c[t+1] < r);
  if (win) {                                           // exactly one thread
    unsigned cum = (t < 255) ? s_c[t+1] : 0u;
    float sab = (t < 255) ? s_s[t+1] : 0.f;
    s_u[0] = (unsigned)t; s_u[1] = r - cum; s_f[0] = sab;
  }
  __syncthreads();
  bin_out = s_u[0]; r_out = s_u[1]; sab_out = s_f[0];
  __syncthreads();
}

// ---------------- K0: zero stats + hist0 + h1 + counter ----------------
__global__ __launch_bounds__(256) void k_zero(uint4* __restrict__ p)
{
  const unsigned i = blockIdx.x * 256u + threadIdx.x;
  if (i < ZERO_WORDS/4) p[i] = make_uint4(0u,0u,0u,0u);
}

// ---------------- K1: per-anchor losses, 16-bit keys, packed level-0 hist ----------------
__global__ __launch_bounds__(256, 4) void k_main(
    const float* __restrict__ pred,
    const float* __restrict__ gtb, const int* __restrict__ gtl,
    unsigned short* __restrict__ keys16, unsigned* __restrict__ stats,
    u64* __restrict__ hist0)
{
  __shared__ float4 s_box[MM];
  __shared__ float s_area[MM], s_gx[MM], s_gy[MM], s_gw[MM], s_gh[MM];
  __shared__ int s_lab[MM];
  __shared__ int s_list[MM];
  __shared__ int s_cnt;
  __shared__ u64 s_h64[8][257];        // packed cnt|sum replicas, +1 pad
  __shared__ unsigned s_ri[2];
  __shared__ float s_rf[3];
  __shared__ unsigned s_plist[AA*256]; // pos items: hw | a<<14 | jb<<18
  __shared__ unsigned s_pcnt;

  const int tid = threadIdx.x;
  const int b = blockIdx.x >> 6;
  const int t6 = blockIdx.x & 63;
  const int tr = t6 >> 3, tc = t6 & 7;            // 8x8 tiles of 16x16 px
  const int hrow = tr*16 + (tid >> 4);
  const int wcol = tc*16 + (tid & 15);
  const int hw = hrow*128 + wcol;

  for (int i = tid; i < 8*257; i += 256) (&s_h64[0][0])[i] = 0ull;
  if (tid == 0) { s_ri[0] = 0u; s_ri[1] = 0u; s_pcnt = 0u; }
  if (tid < 3) s_rf[tid] = 0.f;
  if (tid < MM) {
    float x1 = gtb[((size_t)b*MM + tid)*4 + 0];
    float y1 = gtb[((size_t)b*MM + tid)*4 + 1];
    float x2 = gtb[((size_t)b*MM + tid)*4 + 2];
    float y2 = gtb[((size_t)b*MM + tid)*4 + 3];
    s_box[tid] = make_float4(x1, y1, x2, y2);
    s_area[tid] = (x2 - x1) * (y2 - y1);
    s_gx[tid] = (x1 + x2) * 0.5f;
    s_gy[tid] = (y1 + y2) * 0.5f;
    s_gw[tid] = fmaxf(x2 - x1, 1e-6f);
    s_gh[tid] = fmaxf(y2 - y1, 1e-6f);
    s_lab[tid] = gtl[(size_t)b*MM + tid];
  }
  __syncthreads();

  // cull boxes that cannot overlap any anchor of this tile (margin 46 > 45.25)
  if (tid < 64) {
    const float cxlo = (float)(tc*64 + 2), cxhi = cxlo + 60.f;
    const float cylo = (float)(tr*64 + 2), cyhi = cylo + 60.f;
    bool keep = false;
    if (tid < MM) {
      float4 bx = s_box[tid];
      keep = (bx.z >= cxlo - 46.f) && (bx.x <= cxhi + 46.f) &&
             (bx.w >= cylo - 46.f) && (bx.y <= cyhi + 46.f);
    }
    unsigned long long mask = __ballot(keep);
    if (keep) s_list[__popcll(mask & ((1ull << tid) - 1ull))] = tid;
    if (tid == 0) s_cnt = (int)__popcll(mask);
  }
  __syncthreads();

  // issue the 9 obj-channel loads EARLY: their ~900cy HBM latency overlaps the IoU loop
  const float* pb = pred + (size_t)b * (AA*KK) * HWSZ + hw;
  float xo[AA];
#pragma unroll
  for (int a = 0; a < AA; ++a) xo[a] = pb[(size_t)((a*KK + 4) * HWSZ)];

  // anchor coords, bit-exact reproduction of make_anchors (scales are powers of 2)
  const float cx = ((float)wcol + 0.5f) * 4.0f;
  const float cy = ((float)hrow + 0.5f) * 4.0f;
  float AX1[AA], AY1[AA], AX2[AA], AY2[AA], AREA[AA];
  {
    const float S0[3] = {16.f, 32.f, 64.f};
    const float Q0[3] = {0.70710678118654752440f, 1.0f, 1.41421356237309504880f};
#pragma unroll
    for (int i = 0; i < 3; ++i)
#pragma unroll
      for (int jj = 0; jj < 3; ++jj) {
        int a = i*3 + jj;
        float w2 = S0[i] * Q0[jj] * 0.5f;
        float h2 = (S0[i] / Q0[jj]) * 0.5f;
        float x1 = cx - w2, x2 = cx + w2;
        float y1 = cy - h2, y2 = cy + h2;
        AX1[a]=x1; AX2[a]=x2; AY1[a]=y1; AY2[a]=y2;
        AREA[a] = (x2 - x1) * (y2 - y1);
      }
  }

  float bnum[AA], bden[AA]; int bi[AA];
#pragma unroll
  for (int a = 0; a < AA; ++a) { bnum[a] = 0.f; bden[a] = 1.f; bi[a] = 0; }

  const int cnt = s_cnt;
  for (int jj = 0; jj < cnt; ++jj) {
    const int j = s_list[jj];
    const float4 bx = s_box[j];
    const float ba = s_area[j];
#pragma unroll
    for (int a = 0; a < AA; ++a) {
      float lx = fmaxf(AX1[a], bx.x);
      float ly = fmaxf(AY1[a], bx.y);
      float rx = fminf(AX2[a], bx.z);
      float ry = fminf(AY2[a], bx.w);
      float wx = fmaxf(rx - lx, 0.f);
      float wy = fmaxf(ry - ly, 0.f);
      float inter = wx * wy;
      float den = (AREA[a] + ba) - inter;        // union >= 256 >> 1e-9
      bool bt = inter * bden[a] > bnum[a] * den; // iou_j > iou_best (ascending j)
      bnum[a] = bt ? inter : bnum[a];
      bden[a] = bt ? den : bden[a];
      bi[a]   = bt ? j : bi[a];
    }
  }

  // tile-major key layout: [b][a][t6][tid] -> waves store 512B contiguous
  unsigned short* kout = keys16 + ((size_t)b * AA) * HWSZ + (t6 << 8) + tid;

  const int rep = tid & 7;
  unsigned npos = 0, nneg = 0;
  float objp = 0.f;

#pragma unroll
  for (int a = 0; a < AA; ++a) {
    // multiply-compare: bden > 0 always; 0.5*bden exact
    bool pos = bnum[a] >= 0.5f * bden[a];
    bool neg = bnum[a] < 0.3f * bden[a];

    float x = xo[a];
    float e = __expf(-fabsf(x));
    float ol = fmaxf(x, 0.f) - (pos ? x : 0.f) + __logf(1.f + e);

    unsigned key = 0u;
    if (neg) {
      key = __float_as_uint(ol);
      ++nneg;
      atomicAdd(&s_h64[rep][key >> 24], ONECNT | (u64)(ol * 1048576.0f + 0.5f));
    }
    kout[(size_t)a * HWSZ] = (unsigned short)(key >> 16);

    if (pos) {
      ++npos;
      objp += ol;
      unsigned idx = atomicAdd(&s_pcnt, 1u);
      s_plist[idx] = (unsigned)hw | ((unsigned)a << 14) | ((unsigned)bi[a] << 18);
    }
  }

  __syncthreads();   // s_plist / s_pcnt complete

  // ---- phase 2: process pos anchors in parallel (no divergent heavy branch) ----
  float cls2 = 0.f, loc2 = 0.f;
  {
    const int pcnt = (int)s_pcnt;
    const float* pball = pred + (size_t)b * (AA*KK) * HWSZ;
    for (int i = tid; i < pcnt; i += 256) {
      unsigned it = s_plist[i];
      int hw2 = (int)(it & 16383u);
      int a2  = (int)((it >> 14) & 15u);
      int jb  = (int)(it >> 18);
      int w2c = hw2 & 127, h2r = hw2 >> 7;
      float cx2 = ((float)w2c + 0.5f) * 4.0f;
      float cy2 = ((float)h2r + 0.5f) * 4.0f;
      int si = a2 / 3, rj = a2 - si*3;
      float s0 = (si == 0) ? 16.f : ((si == 1) ? 32.f : 64.f);
      float q0 = (rj == 0) ? 0.70710678118654752440f : ((rj == 1) ? 1.0f : 1.41421356237309504880f);
      float w2 = s0 * q0 * 0.5f;
      float h2 = (s0 / q0) * 0.5f;
      float ax1 = cx2 - w2, ax2 = cx2 + w2;
      float ay1 = cy2 - h2, ay2 = cy2 + h2;

      const float* pp = pball + hw2;
      float c0 = pp[(size_t)((a2*KK + 5) * HWSZ)];
      float c1 = pp[(size_t)((a2*KK + 6) * HWSZ)];
      float c2 = pp[(size_t)((a2*KK + 7) * HWSZ)];
      int lab = s_lab[jb];
      int tgt = lab - 1; tgt = tgt < 0 ? 0 : (tgt > CC-1 ? CC-1 : tgt);
      float m = fmaxf(fmaxf(c0, c1), c2);
      float lse = m + __logf(__expf(c0-m) + __expf(c1-m) + __expf(c2-m));
      float ct = (tgt == 0) ? c0 : ((tgt == 1) ? c1 : c2);
      cls2 += lse - ct;

      float axc = (ax1 + ax2) * 0.5f;
      float ayc = (ay1 + ay2) * 0.5f;
      float aw = fmaxf(ax2 - ax1, 1e-6f);
      float ah = fmaxf(ay2 - ay1, 1e-6f);
      float t0 = (s_gx[jb] - axc) / aw;
      float t1 = (s_gy[jb] - ayc) / ah;
      float t2 = __logf(s_gw[jb] / aw);
      float t3 = __logf(s_gh[jb] / ah);
      float p0 = pp[(size_t)((a2*KK + 0) * HWSZ)];
      float p1 = pp[(size_t)((a2*KK + 1) * HWSZ)];
      float p2 = pp[(size_t)((a2*KK + 2) * HWSZ)];
      float p3 = pp[(size_t)((a2*KK + 3) * HWSZ)];
      float l = 0.f, d, ad;
      d = p0-t0; ad = fabsf(d); l += (ad < 1.f) ? 0.5f*d*d : ad - 0.5f;
      d = p1-t1; ad = fabsf(d); l += (ad < 1.f) ? 0.5f*d*d : ad - 0.5f;
      d = p2-t2; ad = fabsf(d); l += (ad < 1.f) ? 0.5f*d*d : ad - 0.5f;
      d = p3-t3; ad = fabsf(d); l += (ad < 1.f) ? 0.5f*d*d : ad - 0.5f;
      loc2 += l;
    }
  }

  // wave-level reduction, one atomic per wave per counter
#pragma unroll
  for (int off = 32; off; off >>= 1) {
    npos += __shfl_down(npos, off);
    nneg += __shfl_down(nneg, off);
    objp += __shfl_down(objp, off);
    cls2 += __shfl_down(cls2, off);
    loc2 += __shfl_down(loc2, off);
  }
  if ((tid & 63) == 0) {
    atomicAdd(&s_ri[0], npos);
    atomicAdd(&s_ri[1], nneg);
    atomicAdd(&s_rf[0], objp);
    atomicAdd(&s_rf[1], cls2);
    atomicAdd(&s_rf[2], loc2);
  }
  __syncthreads();

  unsigned* st = stats + b * STATS_STRIDE;
  if (tid == 0) { atomicAdd(&st[ST_NPOS], s_ri[0]); atomicAdd(&st[ST_NNEG], s_ri[1]); }
  else if (tid == 1) atomicAdd((float*)(st + ST_OBJP), s_rf[0]);
  else if (tid == 2) atomicAdd((float*)(st + ST_CLS), s_rf[1]);
  else if (tid == 3) atomicAdd((float*)(st + ST_LOC), s_rf[2]);

  u64 m = 0ull;
#pragma unroll
  for (int r = 0; r < 8; ++r) m += s_h64[r][tid];
  if (m) atomicAdd(&hist0[b*256 + tid], m);
}

// ---- H1: scan 16-bit keys — count-only 256-bin hist of low byte under bin0 ----
__global__ __launch_bounds__(256) void k_h1(
    const unsigned short* __restrict__ keys16, const unsigned* __restrict__ stats,
    const u64* __restrict__ hist0, unsigned* __restrict__ h1)
{
  __shared__ unsigned s_c[256]; __shared__ float s_s[256];
  __shared__ unsigned s_u[2];   __shared__ float s_f[1];
  __shared__ unsigned s_hc[8][257];
  const int tid = threadIdx.x;
  const int b = blockIdx.x >> 4;                  // 16 blocks/image
  const unsigned* st = stats + b * STATS_STRIDE;
  const unsigned k = calc_k(st[ST_NPOS], st[ST_NNEG]);
  if (k == 0u) return;

  unsigned bin0, r0; float sab;
  {
    u64 v = hist0[b*256 + tid];
    sel1((unsigned)(v >> 44), (float)(v & SUMMASK) * 0x1p-20f, k,
         s_c, s_s, s_u, s_f, bin0, r0, sab);
  }

  for (int i = tid; i < 8*257; i += 256) (&s_hc[0][0])[i] = 0u;
  __syncthreads();

  const int rep = tid & 7;
  // 9216 keys/block = 2304 uint2 (4 ushorts each) / 256 threads = 9 iters
  const uint2* kp = (const uint2*)(keys16 + (size_t)b * NN) +
                    (size_t)(blockIdx.x & 15) * 2304;
#pragma unroll
  for (int j = 0; j < 9; ++j) {
    uint2 v = kp[j*256 + tid];
    unsigned k0 = v.x & 0xFFFFu, k1 = v.x >> 16;
    unsigned k2 = v.y & 0xFFFFu, k3 = v.y >> 16;
    if ((k0 >> 8) == bin0) atomicAdd(&s_hc[rep][k0 & 255u], 1u);
    if ((k1 >> 8) == bin0) atomicAdd(&s_hc[rep][k1 & 255u], 1u);
    if ((k2 >> 8) == bin0) atomicAdd(&s_hc[rep][k2 & 255u], 1u);
    if ((k3 >> 8) == bin0) atomicAdd(&s_hc[rep][k3 & 255u], 1u);
  }
  __syncthreads();

  unsigned c = 0;
#pragma unroll
  for (int r = 0; r < 8; ++r) c += s_hc[r][tid];
  if (c) atomicAdd(&h1[b*256 + tid], c);
}

// ---- FIN: per-image two-level select (16 blocks); last-done block combines ----
// Bins above bin1 summed from packed hist (2^-20 fixed point, error ~5e-7 on loss);
// bin0's interior at mid-bin (16-bit bins, unbiased): worst-case loss error ~4e-3.
__global__ __launch_bounds__(256) void k_fin(
    const u64* __restrict__ hist0, const unsigned* __restrict__ h1,
    unsigned* __restrict__ stats, unsigned* __restrict__ counter,
    float* __restrict__ out)
{
  __shared__ unsigned s_c[256]; __shared__ float s_s[256];
  __shared__ unsigned s_u[2];   __shared__ float s_f[1];
  __shared__ unsigned s_prev;
  const int b = blockIdx.x;
  const int tid = threadIdx.x;
  unsigned* st = stats + b * STATS_STRIDE;
  const unsigned k = calc_k(st[ST_NPOS], st[ST_NNEG]);
  float topk = 0.f;
  if (k) {
    unsigned bin0, r0, bin1, r1;
    float sab0, sab1;
    {
      u64 v = hist0[b*256 + tid];
      sel1((unsigned)(v >> 44), (float)(v & SUMMASK) * 0x1p-20f, k,
           s_c, s_s, s_u, s_f, bin0, r0, sab0);
    }
    unsigned c1 = h1[b*256 + tid];
    float mid = __uint_as_float((bin0 << 24) | ((unsigned)tid << 16) | 0x8000u);
    sel1(c1, (float)c1 * mid, r0, s_c, s_s, s_u, s_f, bin1, r1, sab1);
    float mid1 = __uint_as_float((bin0 << 24) | (bin1 << 16) | 0x8000u);
    topk = sab0 + sab1 + (float)r1 * mid1;
  }
  if (tid == 0) {
    __hip_atomic_store(&st[ST_K], k, __ATOMIC_RELAXED, __HIP_MEMORY_SCOPE_AGENT);
    __hip_atomic_store((float*)&st[ST_TOPK], topk, __ATOMIC_RELAXED, __HIP_MEMORY_SCOPE_AGENT);
    __threadfence();   // release prior stores device-wide
    s_prev = __hip_atomic_fetch_add(counter, 1u, __ATOMIC_ACQ_REL, __HIP_MEMORY_SCOPE_AGENT);
  }
  __syncthreads();

  if (s_prev == (unsigned)(BB - 1) && tid < 64) {
    unsigned np = 0, kk = 0;
    float obj = 0.f, cls = 0.f, loc = 0.f;
    if (tid < BB) {
      unsigned* s2 = stats + tid * STATS_STRIDE;
      np  = s2[ST_NPOS];                       // from k_main (kernel boundary)
      cls = ((const float*)s2)[ST_CLS];
      loc = ((const float*)s2)[ST_LOC];
      obj = ((const float*)s2)[ST_OBJP];
      kk  = __hip_atomic_load(&s2[ST_K], __ATOMIC_RELAXED, __HIP_MEMORY_SCOPE_AGENT);
      float tk = __hip_atomic_load((float*)&s2[ST_TOPK], __ATOMIC_ACQUIRE, __HIP_MEMORY_SCOPE_AGENT);
      obj += tk;
    }
#pragma unroll
    for (int off = 8; off; off >>= 1) {
      np  += __shfl_down(np, off);
      kk  += __shfl_down(kk, off);
      obj += __shfl_down(obj, off);
      cls += __shfl_down(cls, off);
      loc += __shfl_down(loc, off);
    }
    if (tid == 0) {
      unsigned ts = np + kk;
      float dp  = (float)(np > 1u ? np : 1u);
      float dob = (float)(ts > 1u ? ts : 1u);
      float lo = obj / dob, lc = cls / dp, ll = loc / dp;
      out[0] = lo;
      out[1] = lc;
      out[2] = ll;
      out[3] = 2.f*ll + lc + lo;
    }
  }
}

extern "C" void kernel_launch(void* const* d_in, const int* in_sizes, int n_in,
                              void* d_out, int out_size, void* d_ws, size_t ws_size,
                              hipStream_t stream)
{
  const float* pred = (const float*)d_in[0];
  // d_in[1] (anchors) reproduced bit-exactly on device; unused
  const float* gtb  = (const float*)d_in[2];
  const int*   gtl  = (const int*)d_in[3];
  float* out = (float*)d_out;

  unsigned* ws    = (unsigned*)d_ws;
  unsigned short* keys16 = (unsigned short*)ws;
  unsigned* stats = ws + KEYS16_WORDS;
  u64* hist0      = (u64*)(stats + STATS_WORDS);   // 8-byte aligned (even word offset)
  unsigned* h1    = (unsigned*)(hist0 + BB*256);
  unsigned* cnt   = h1 + H1_WORDS;

  k_zero<<<(ZERO_WORDS/4 + 255)/256, 256, 0, stream>>>((uint4*)stats);
  k_main<<<BB*64, 256, 0, stream>>>(pred, gtb, gtl, keys16, stats, hist0);
  k_h1<<<BB*HBLK, 256, 0, stream>>>(keys16, stats, hist0, h1);
  k_fin<<<BB, 256, 0, stream>>>(hist0, h1, stats, cnt, out);
}